// Round 1
// 1528.005 us; speedup vs baseline: 1.0247x; 1.0247x over previous
//
#include <hip/hip_runtime.h>
#include <hip/hip_bf16.h>

// LuongAttention on MI355X — round 3.
// P = Q@W^T and S = P@V^T as PLAIN bf16 GEMMs with K'=3K plane-concat
// ([Ahi,Ahi,Alo]·[Bhi,Blo,Bhi]^T == hi*hi + hi*lo + lo*hi), run on a
// 256x256x64 8-phase pipelined kernel (m201 structure): counted vmcnt(6),
// LDS XOR-swizzle via pre-swizzled global source, s_setprio around MFMA.
// Context GEMM uses the same kernel on a bf16 alignment copy (ws-guarded,
// fallback = previous m97-style gemm_ctx).

#define B_  16
#define TQ_ 2048
#define TV_ 2048
#define D_  1024
#define U_  1024

typedef __attribute__((ext_vector_type(8))) short bf16x8;  // 8 bf16 = 4 VGPRs
typedef __attribute__((ext_vector_type(4))) float f32x4;

__device__ __forceinline__ short f2bf(float x) {
    union { float f; unsigned u; } v; v.f = x;
    unsigned r = v.u + 0x7fffu + ((v.u >> 16) & 1u);   // RNE
    return (short)(r >> 16);
}
__device__ __forceinline__ float bf2f(short h) {
    union { unsigned u; float f; } v;
    v.u = ((unsigned)(unsigned short)h) << 16;
    return v.f;
}

// async global->LDS, 16B per lane; lds base must be wave-uniform (m104/m108)
__device__ __forceinline__ void gld16(const short* g, short* l) {
    __builtin_amdgcn_global_load_lds(
        (const __attribute__((address_space(1))) void*)g,
        (__attribute__((address_space(3))) void*)l, 16, 0, 0);
}

// ---------------------------------------------------------------------------
// 8-phase 256x256 NT GEMM, BK=64, 8 waves (2M x 4N), LDS 128 KiB dbuf.
// NPLANES=3: K' = 3*KT*64 with plane select A:[hi,hi,lo] B:[hi,lo,hi].
// NPLANES=1: plain bf16, K = KT*64.
// SPLIT_OUT=1: emit (Chi,Clo) bf16 planes; else fp32 C.
// LDS swizzle: 16B slot s of row r holds logical slot s^(r&7); staging
// pre-swizzles the GLOBAL source column so gld16 dests stay linear (m173).
// Schedule safety: B-tile fully ds_read at phase1, A-lo at p1, A-hi at p3;
// every stage-issue is >=1 barrier after the target region's last read
// (drained by the lgkmcnt(0) before that phase's MFMAs). vmcnt(6) once per
// K-tile leaves exactly the 3 newest half-tiles in flight.
// ---------------------------------------------------------------------------
#define MFMA_QUAD(MB, NB)                                                       \
    __builtin_amdgcn_s_setprio(1);                                              \
    _Pragma("unroll")                                                           \
    for (int mf = 0; mf < 4; ++mf)                                              \
        _Pragma("unroll")                                                       \
        for (int nf = 0; nf < 2; ++nf)                                          \
            _Pragma("unroll")                                                   \
            for (int ks = 0; ks < 2; ++ks)                                      \
                acc[(MB) + mf][(NB) + nf] =                                     \
                    __builtin_amdgcn_mfma_f32_16x16x32_bf16(                    \
                        afr[mf][ks], bfr[(NB) + nf][ks],                        \
                        acc[(MB) + mf][(NB) + nf], 0, 0, 0);                    \
    __builtin_amdgcn_s_setprio(0);

template<int NPLANES, int SPLIT_OUT, int KT>
__global__ __launch_bounds__(512, 2) void gemm8(
    const short* __restrict__ Ahi, const short* __restrict__ Alo,
    const short* __restrict__ Bhi, const short* __restrict__ Blo,
    float* __restrict__ C, short* __restrict__ Chi, short* __restrict__ Clo,
    int lda, int ldb, int ldc, size_t sAz, size_t sBz, size_t sCz)
{
    constexpr int NT = NPLANES * KT;          // K-tiles of 64
    __shared__ short sA[2][16384];            // [buf][256 rows * 64 k]
    __shared__ short sB[2][16384];

    const int tid  = threadIdx.x;
    const int lane = tid & 63, wid = tid >> 6;
    const int wm = (wid >> 2) << 7;           // 0 / 128
    const int wn = (wid & 3) << 6;            // 0 / 64 / 128 / 192
    const int l15 = lane & 15, l4 = lane >> 4, l7 = lane & 7;
    // staging: thread covers physical 16B slot (tid&7) of row (tid>>3);
    // fetch logical slot (tid&7)^(row&7)  (inverse-swizzle on source)
    const int sr   = tid >> 3;
    const int colS = ((tid & 7) ^ (sr & 7)) << 3;   // shorts
    const int wvB  = wid << 9;                       // wave LDS base (shorts)

    const size_t z    = blockIdx.z;
    const size_t row0 = (size_t)blockIdx.y << 8;
    const size_t col0 = (size_t)blockIdx.x << 8;
    const short* Abh = Ahi + z * sAz + row0 * (size_t)lda;
    const short* Abl = (NPLANES == 3) ? Alo + z * sAz + row0 * (size_t)lda : nullptr;
    const short* Bbh = Bhi + z * sBz + col0 * (size_t)ldb;
    const short* Bbl = (NPLANES == 3) ? Blo + z * sBz + col0 * (size_t)ldb : nullptr;

    auto aSrc = [&](int t) -> const short* {
        const int p = t / KT;                                  // constexpr KT -> shift
        const short* base = (NPLANES == 3 && p == 2) ? Abl : Abh;
        return base + ((t - p * KT) << 6);
    };
    auto bSrc = [&](int t) -> const short* {
        const int p = t / KT;
        const short* base = (NPLANES == 3 && p == 1) ? Bbl : Bbh;
        return base + ((t - p * KT) << 6);
    };
    auto stageA = [&](int t, int h) {                          // half = 128 rows, 2 issues
        const short* g = aSrc(t) + (size_t)((h << 7) + sr) * lda + colS;
        short* l = &sA[t & 1][(h << 13) + wvB];
        gld16(g, l);
        gld16(g + (size_t)(lda << 6), l + 4096);
    };
    auto stageB = [&](int t, int h) {
        const short* g = bSrc(t) + (size_t)((h << 7) + sr) * ldb + colS;
        short* l = &sB[t & 1][(h << 13) + wvB];
        gld16(g, l);
        gld16(g + (size_t)(ldb << 6), l + 4096);
    };

    f32x4 acc[8][4];
    #pragma unroll
    for (int i = 0; i < 8; ++i)
        #pragma unroll
        for (int j = 0; j < 4; ++j)
            acc[i][j] = (f32x4){0.f, 0.f, 0.f, 0.f};

    // prologue: tile0 fully, tile1 B,B,A0 (A1 comes in t=0 phase1)
    stageB(0, 0); stageB(0, 1); stageA(0, 0); stageA(0, 1);
    stageB(1, 0); stageB(1, 1); stageA(1, 0);
    asm volatile("s_waitcnt vmcnt(6)" ::: "memory");           // tile0 landed
    __builtin_amdgcn_s_barrier();

    #pragma unroll 1
    for (int t = 0; t < NT; ++t) {
        const short* sAb = sA[t & 1];
        const short* sBb = sB[t & 1];
        bf16x8 afr[4][2], bfr[4][2];

        // ---- phase 1: ds-read B(all)+A(lo) | stage A-h1(t+1) | MFMA Mlo,Nlo
        #pragma unroll
        for (int nf = 0; nf < 4; ++nf)
            #pragma unroll
            for (int ks = 0; ks < 2; ++ks)
                bfr[nf][ks] = *(const bf16x8*)&sBb[((wn + (nf << 4) + l15) << 6)
                                + ((((ks << 2) | l4) ^ l7) << 3)];
        #pragma unroll
        for (int mf = 0; mf < 4; ++mf)
            #pragma unroll
            for (int ks = 0; ks < 2; ++ks)
                afr[mf][ks] = *(const bf16x8*)&sAb[((wm + (mf << 4) + l15) << 6)
                                + ((((ks << 2) | l4) ^ l7) << 3)];
        if (t + 1 < NT) stageA(t + 1, 1);
        __builtin_amdgcn_s_barrier();
        asm volatile("s_waitcnt lgkmcnt(0)" ::: "memory");
        __builtin_amdgcn_sched_barrier(0);
        MFMA_QUAD(0, 0)
        __builtin_amdgcn_s_barrier();

        // ---- phase 2: stage B-h0(t+2) | MFMA Mlo,Nhi (regs only)
        if (t + 2 < NT) stageB(t + 2, 0);
        __builtin_amdgcn_s_barrier();
        MFMA_QUAD(0, 2)
        __builtin_amdgcn_s_barrier();

        // ---- phase 3: ds-read A(hi) | stage B-h1(t+2) | MFMA Mhi,Nhi
        #pragma unroll
        for (int mf = 0; mf < 4; ++mf)
            #pragma unroll
            for (int ks = 0; ks < 2; ++ks)
                afr[mf][ks] = *(const bf16x8*)&sAb[((wm + 64 + (mf << 4) + l15) << 6)
                                + ((((ks << 2) | l4) ^ l7) << 3)];
        if (t + 2 < NT) stageB(t + 2, 1);
        __builtin_amdgcn_s_barrier();
        asm volatile("s_waitcnt lgkmcnt(0)" ::: "memory");
        __builtin_amdgcn_sched_barrier(0);
        MFMA_QUAD(4, 2)
        __builtin_amdgcn_s_barrier();

        // ---- phase 4: stage A-h0(t+2) | MFMA Mhi,Nlo | counted vmcnt
        if (t + 2 < NT) stageA(t + 2, 0);
        __builtin_amdgcn_s_barrier();
        MFMA_QUAD(4, 0)
        if (t < NT - 2)       asm volatile("s_waitcnt vmcnt(6)" ::: "memory");
        else if (t == NT - 2) asm volatile("s_waitcnt vmcnt(0)" ::: "memory");
        __builtin_amdgcn_s_barrier();
    }

    // C/D layout (16x16x32): col = lane&15, row = (lane>>4)*4 + reg  [m89/m91]
    if (SPLIT_OUT) {
        #pragma unroll
        for (int mf = 0; mf < 8; ++mf)
            #pragma unroll
            for (int nf = 0; nf < 4; ++nf)
                #pragma unroll
                for (int r = 0; r < 4; ++r) {
                    const float x = acc[mf][nf][r];
                    const short h = f2bf(x);
                    const short lo = f2bf(x - bf2f(h));
                    const size_t idx = (row0 + wm + (mf << 4) + (l4 << 2) + r) * (size_t)ldc
                                       + col0 + wn + (nf << 4) + l15;
                    Chi[idx] = h;
                    Clo[idx] = lo;
                }
    } else {
        float* Cb = C + z * sCz;
        #pragma unroll
        for (int mf = 0; mf < 8; ++mf)
            #pragma unroll
            for (int nf = 0; nf < 4; ++nf)
                #pragma unroll
                for (int r = 0; r < 4; ++r)
                    Cb[(row0 + wm + (mf << 4) + (l4 << 2) + r) * (size_t)ldc
                       + col0 + wn + (nf << 4) + l15] = acc[mf][nf][r];
    }
}

// ---------------------------------------------------------------------------
// FALLBACK (ws too small for bf16 alignment copy):
// context = A[M,K] . Bt[N,K]^T; A fp32 (fused bf16 convert), Bt bf16
// ---------------------------------------------------------------------------
__global__ __launch_bounds__(256, 2) void gemm_ctx(
    const float* __restrict__ A, const short* __restrict__ Bt, float* __restrict__ C,
    int lda, int ldb, int ldc, int K, size_t sA, size_t sB, size_t sC)
{
    __shared__ short sA16[128 * 32], sB16[128 * 32];
    const int tid = threadIdx.x;
    const int lane = tid & 63, wave = tid >> 6;
    const int wm = (wave >> 1) << 6, wn = (wave & 1) << 6;
    const int l15 = lane & 15, l4 = lane >> 4;
    const int lr = lane >> 2, lc = (lane & 3) << 3;
    const size_t row0 = (size_t)blockIdx.y << 7, col0 = (size_t)blockIdx.x << 7;
    const float* Ab = A + (size_t)blockIdx.z * sA + row0 * (size_t)lda;
    const short* Bb = Bt + (size_t)blockIdx.z * sB + col0 * (size_t)ldb;

    f32x4 acc[4][4];
    for (int i = 0; i < 4; ++i)
        for (int j = 0; j < 4; ++j)
            acc[i][j] = (f32x4){0.f, 0.f, 0.f, 0.f};

    for (int kt = 0; kt < K; kt += 32) {
        __syncthreads();
        for (int r = 0; r < 4; ++r) {
            const int flat = (r << 8) + tid;
            const int row = flat >> 3, c = (flat & 7) << 2;
            const float4 va = *(const float4*)(Ab + (size_t)row * lda + kt + c);
            short4 h;
            h.x = f2bf(va.x); h.y = f2bf(va.y); h.z = f2bf(va.z); h.w = f2bf(va.w);
            *(short4*)&sA16[(row << 5) + c] = h;
        }
        for (int t = 0; t < 2; ++t) {
            const int rbase = (wave << 5) + (t << 4);
            gld16(Bb + (size_t)(rbase + lr) * ldb + kt + lc, &sB16[rbase << 5]);
        }
        __syncthreads();
        const int ko = l4 << 3;
        bf16x8 ah[4], bh[4];
        for (int i = 0; i < 4; ++i) {
            ah[i] = *(const bf16x8*)&sA16[((wm + (i << 4) + l15) << 5) + ko];
            bh[i] = *(const bf16x8*)&sB16[((wn + (i << 4) + l15) << 5) + ko];
        }
        for (int i = 0; i < 4; ++i)
            for (int j = 0; j < 4; ++j)
                acc[i][j] = __builtin_amdgcn_mfma_f32_16x16x32_bf16(ah[i], bh[j], acc[i][j], 0, 0, 0);
    }

    float* Cb = C + (size_t)blockIdx.z * sC;
    for (int i = 0; i < 4; ++i)
        for (int j = 0; j < 4; ++j)
            for (int r = 0; r < 4; ++r)
                Cb[(row0 + wm + (i << 4) + (l4 << 2) + r) * (size_t)ldc
                   + col0 + wn + (j << 4) + l15] = acc[i][j][r];
}

// elementwise fp32 -> (hi,lo) bf16 planes, 4 elems/thread
__global__ __launch_bounds__(256) void split_f32(
    const float* __restrict__ X, short* __restrict__ hi, short* __restrict__ lo)
{
    const size_t i = ((size_t)blockIdx.x * 256 + threadIdx.x) << 2;
    const float4 v = *(const float4*)(X + i);
    short4 h, l;
    h.x = f2bf(v.x); l.x = f2bf(v.x - bf2f(h.x));
    h.y = f2bf(v.y); l.y = f2bf(v.y - bf2f(h.y));
    h.z = f2bf(v.z); l.z = f2bf(v.z - bf2f(h.z));
    h.w = f2bf(v.w); l.w = f2bf(v.w - bf2f(h.w));
    *(short4*)(hi + i) = h;
    *(short4*)(lo + i) = l;
}

// values[b][v][d] -> Vhi/Vlo (same layout) + Vt[b][d][v] bf16 (hi only)
__global__ __launch_bounds__(256) void split_values(
    const float* __restrict__ V, short* __restrict__ Vhi,
    short* __restrict__ Vlo, short* __restrict__ Vt)
{
    __shared__ float tile[32][33];
    const int b = blockIdx.z;
    const int d0 = blockIdx.x << 5, v0 = blockIdx.y << 5;
    const float* Vb = V + (size_t)b * TV_ * D_;
    const size_t pb = (size_t)b * TV_ * D_;
    short* Vtb = Vt + (size_t)b * D_ * TV_;
    const int tx = threadIdx.x, ty = threadIdx.y;   // 32 x 8
    for (int k = 0; k < 4; ++k) {
        const int v = v0 + ty + (k << 3);
        const float x = Vb[(size_t)v * D_ + d0 + tx];
        tile[ty + (k << 3)][tx] = x;
        const short h = f2bf(x);
        Vhi[pb + (size_t)v * D_ + d0 + tx] = h;
        Vlo[pb + (size_t)v * D_ + d0 + tx] = f2bf(x - bf2f(h));
    }
    __syncthreads();
    for (int k = 0; k < 4; ++k)
        Vtb[(size_t)(d0 + ty + (k << 3)) * TV_ + v0 + tx] = f2bf(tile[tx][ty + (k << 3)]);
}

// in-place softmax over rows of length 2048; optional bf16 copy for ctx GEMM
__global__ __launch_bounds__(256) void softmax_rows(
    float* __restrict__ S, short* __restrict__ A16)
{
    float* p = S + (size_t)blockIdx.x * TV_;
    const int t = threadIdx.x;
    const int lane = t & 63, wave = t >> 6;
    float4 a = *(const float4*)(p + (t << 2));
    float4 b = *(const float4*)(p + 1024 + (t << 2));
    float m = fmaxf(fmaxf(fmaxf(a.x, a.y), fmaxf(a.z, a.w)),
                    fmaxf(fmaxf(b.x, b.y), fmaxf(b.z, b.w)));
    for (int off = 32; off; off >>= 1) m = fmaxf(m, __shfl_xor(m, off, 64));
    __shared__ float redm[4], reds[4];
    if (lane == 0) redm[wave] = m;
    __syncthreads();
    m = fmaxf(fmaxf(redm[0], redm[1]), fmaxf(redm[2], redm[3]));
    a.x = __expf(a.x - m); a.y = __expf(a.y - m);
    a.z = __expf(a.z - m); a.w = __expf(a.w - m);
    b.x = __expf(b.x - m); b.y = __expf(b.y - m);
    b.z = __expf(b.z - m); b.w = __expf(b.w - m);
    float s = a.x + a.y + a.z + a.w + b.x + b.y + b.z + b.w;
    for (int off = 32; off; off >>= 1) s += __shfl_xor(s, off, 64);
    if (lane == 0) reds[wave] = s;
    __syncthreads();
    s = reds[0] + reds[1] + reds[2] + reds[3];
    const float inv = 1.0f / s;
    a.x *= inv; a.y *= inv; a.z *= inv; a.w *= inv;
    b.x *= inv; b.y *= inv; b.z *= inv; b.w *= inv;
    *(float4*)(p + (t << 2)) = a;
    *(float4*)(p + 1024 + (t << 2)) = b;
    if (A16) {
        short* q = A16 + (size_t)blockIdx.x * TV_;
        short4 ha, hb;
        ha.x = f2bf(a.x); ha.y = f2bf(a.y); ha.z = f2bf(a.z); ha.w = f2bf(a.w);
        hb.x = f2bf(b.x); hb.y = f2bf(b.y); hb.z = f2bf(b.z); hb.w = f2bf(b.w);
        *(short4*)(q + (t << 2)) = ha;
        *(short4*)(q + 1024 + (t << 2)) = hb;
    }
}

extern "C" void kernel_launch(void* const* d_in, const int* in_sizes, int n_in,
                              void* d_out, int out_size, void* d_ws, size_t ws_size,
                              hipStream_t stream)
{
    const float* query  = (const float*)d_in[0];   // [16,2048,1024]
    const float* values = (const float*)d_in[1];   // [16,2048,1024]
    const float* Wk     = (const float*)d_in[2];   // [1024,1024]  (bias unused)

    const size_t NQ = (size_t)B_ * TQ_ * D_;       // 33554432
    const size_t NV = (size_t)B_ * TV_ * D_;
    const size_t NW = (size_t)D_ * U_;             // 1048576
    const size_t NA = (size_t)B_ * TQ_ * TV_;      // 67108864

    float* context = (float*)d_out;                          // [16,2048,1024] fp32
    float* align   = (float*)d_out + NQ;                     // [16,2048,2048] fp32

    // context region doubles as P planes (dead before context written)
    short* Phi = (short*)d_out;
    short* Plo = Phi + NQ;
    // align region doubles as Q planes (dead before S written)
    short* Qhi = (short*)align;
    short* Qlo = Qhi + NQ;
    // ws: W planes (4MB) + V planes (128MB) + Vt (64MB) [+ A16 bf16 copy 128MB]
    short* Whi = (short*)d_ws;
    short* Wlo = Whi + NW;
    short* Vhi = Wlo + NW;
    short* Vlo = Vhi + NV;
    short* Vt  = Vlo + NV;
    const size_t WS_NEED = (2 * NW + 3 * NV + NA) * sizeof(short);
    short* A16 = (ws_size >= WS_NEED) ? (Vt + NV) : nullptr;

    // 1. splits
    split_f32<<<NQ / 1024, 256, 0, stream>>>(query, Qhi, Qlo);
    split_f32<<<NW / 1024, 256, 0, stream>>>(Wk, Whi, Wlo);
    split_values<<<dim3(D_ / 32, TV_ / 32, B_), dim3(32, 8), 0, stream>>>(
        values, Vhi, Vlo, Vt);

    // 2. P = Q @ W^T  (M=32768, N=1024, K'=3*1024) -> (Phi,Plo) planes
    gemm8<3, 1, 16><<<dim3(D_ / 256, (B_ * TQ_) / 256, 1), 512, 0, stream>>>(
        Qhi, Qlo, Whi, Wlo, nullptr, Phi, Plo, U_, U_, D_, 0, 0, 0);

    // 3. S = P @ V^T per batch (M=N=2048, K'=3*1024) -> raw scores into align
    gemm8<3, 0, 16><<<dim3(TV_ / 256, TQ_ / 256, B_), 512, 0, stream>>>(
        Phi, Plo, Vhi, Vlo, align, nullptr, nullptr, D_, D_, TV_,
        (size_t)TQ_ * D_, (size_t)TV_ * D_, (size_t)TQ_ * TV_);

    // 4. softmax in place (+ bf16 copy when ws allows)
    softmax_rows<<<B_ * TQ_, 256, 0, stream>>>(align, A16);

    // 5. context = alignment @ V per batch
    if (A16)
        gemm8<1, 0, 32><<<dim3(D_ / 256, TQ_ / 256, B_), 512, 0, stream>>>(
            A16, nullptr, Vt, nullptr, context, nullptr, nullptr, TV_, TV_, D_,
            (size_t)TQ_ * TV_, (size_t)D_ * TV_, (size_t)TQ_ * D_);
    else
        gemm_ctx<<<dim3(D_ / 128, TQ_ / 128, B_), 256, 0, stream>>>(
            align, Vt, context, TV_, TV_, D_, TV_,
            (size_t)TQ_ * TV_, (size_t)D_ * TV_, (size_t)TQ_ * D_);
}

// Round 2
// 1427.911 us; speedup vs baseline: 1.0965x; 1.0701x over previous
//
#include <hip/hip_runtime.h>
#include <hip/hip_bf16.h>

// LuongAttention on MI355X — round 4.
// Same decomposition as round 3 (K'=3K bf16 plane-concat GEMMs), but the
// 256x256x64 kernel is rebuilt with TRUE one-phase read-ahead:
//   - no forced lgkmcnt(0): every ds_read is issued >=1 phase before its
//     consuming MFMA quad; compiler emits counted lgkm waits.
//   - register role rotation (A set reused lo->hi->lo', B sets swap per
//     tile, 2-tile unrolled loop, all indices compile-time).
//   - staging staggered [P3: B-h0 | P4: A-h0,A-h1,B-h1] so a single
//     vmcnt(2)+barrier per K-tile guarantees DMA landing for all waves
//     (vmcnt is per-wave: the wait must precede a barrier that precedes
//     the dependent cross-wave reads). Tail tiles use vmcnt(0).
//   - 4 barriers/tile (was 8), setprio around MFMA quads, XCD-bijective
//     block swizzle (all grids divisible by 8).

#define B_  16
#define TQ_ 2048
#define TV_ 2048
#define D_  1024
#define U_  1024

typedef __attribute__((ext_vector_type(8))) short bf16x8;  // 8 bf16 = 4 VGPRs
typedef __attribute__((ext_vector_type(4))) float f32x4;

__device__ __forceinline__ short f2bf(float x) {
    union { float f; unsigned u; } v; v.f = x;
    unsigned r = v.u + 0x7fffu + ((v.u >> 16) & 1u);   // RNE
    return (short)(r >> 16);
}
__device__ __forceinline__ float bf2f(short h) {
    union { unsigned u; float f; } v;
    v.u = ((unsigned)(unsigned short)h) << 16;
    return v.f;
}

// async global->LDS, 16B per lane; lds base must be wave-uniform (m104/m108)
__device__ __forceinline__ void gld16(const short* g, short* l) {
    __builtin_amdgcn_global_load_lds(
        (const __attribute__((address_space(1))) void*)g,
        (__attribute__((address_space(3))) void*)l, 16, 0, 0);
}

#define CFENCE asm volatile("" ::: "memory")
#define BAR()  do { CFENCE; __builtin_amdgcn_s_barrier(); CFENCE; } while (0)

// ---- fragment loads (XOR-swizzled column slot, conflict-free: verified
//      round 3, SQ_LDS_BANK_CONFLICT == 0) --------------------------------
#define LDA_HALF(dst, sAb, half)                                            \
    _Pragma("unroll")                                                       \
    for (int mf = 0; mf < 4; ++mf)                                          \
        _Pragma("unroll")                                                   \
        for (int ks = 0; ks < 2; ++ks)                                      \
            dst[mf][ks] = *(const bf16x8*)&(sAb)[((wm + ((half) << 6) + (mf << 4) + l15) << 6) \
                            + ((((ks << 2) | l4) ^ l7) << 3)];

#define LDB_PAIR(dst, sBb, pair)                                            \
    _Pragma("unroll")                                                       \
    for (int nf = 0; nf < 2; ++nf)                                          \
        _Pragma("unroll")                                                   \
        for (int ks = 0; ks < 2; ++ks)                                      \
            dst[nf][ks] = *(const bf16x8*)&(sBb)[((wn + ((((pair) << 1) | nf) << 4) + l15) << 6) \
                            + ((((ks << 2) | l4) ^ l7) << 3)];

#define QUAD(MB, NB, BG)                                                    \
    __builtin_amdgcn_s_setprio(1);                                          \
    _Pragma("unroll")                                                       \
    for (int mf = 0; mf < 4; ++mf)                                          \
        _Pragma("unroll")                                                   \
        for (int nf = 0; nf < 2; ++nf)                                      \
            _Pragma("unroll")                                               \
            for (int ks = 0; ks < 2; ++ks)                                  \
                acc[(MB) + mf][(NB) + nf] = __builtin_amdgcn_mfma_f32_16x16x32_bf16( \
                    afr[mf][ks], BG[nf][ks], acc[(MB) + mf][(NB) + nf], 0, 0, 0);    \
    __builtin_amdgcn_s_setprio(0);

// One K-tile = 4 phases. Reads always >=1 phase ahead of consumption:
//   enter with afr = Alo(t), B01 = B01(t)   (read last tile P4 / prologue)
//   P1: read B23(t)          | Q1 = (0,0) AloxB01
//   P2: Q2 = (0,2) AloxB23   | read Ahi(t) -> afr (WAR after Q2)
//   P3: stage B(t+2,h0)      | Q3 = (4,2) AhixB23 | vmcnt(2 or 0) drain
//   P4: stage A(t+2,h0/h1), B(t+2,h1) | Q4 = (4,0) AhixB01
//       | read Alo(t+1)->afr, B01(t+1)->B23set (role swap)
// Region lifetimes vs DMA writes verified: every stage targets a region
// whose last ds_read was consumed by an MFMA before a preceding barrier;
// every read's staging DMA is drained by the prior tile's vmcnt+barrier.
#define TILE(t, B01, B23)                                                   \
    do {                                                                    \
        const short* sAb = sA[(t) & 1];                                     \
        const short* sBb = sB[(t) & 1];                                     \
        LDB_PAIR(B23, sBb, 1)                                               \
        QUAD(0, 0, B01)                                                     \
        BAR();                                                              \
        QUAD(0, 2, B23)                                                     \
        LDA_HALF(afr, sAb, 1)                                               \
        BAR();                                                              \
        if ((t) + 2 < NT) stageB((t) + 2, 0);                               \
        QUAD(4, 2, B23)                                                     \
        if ((t) + 2 < NT) { asm volatile("s_waitcnt vmcnt(2)" ::: "memory"); } \
        else              { asm volatile("s_waitcnt vmcnt(0)" ::: "memory"); } \
        BAR();                                                              \
        if ((t) + 2 < NT) {                                                 \
            stageA((t) + 2, 0); stageA((t) + 2, 1); stageB((t) + 2, 1);     \
        }                                                                   \
        QUAD(4, 0, B01)                                                     \
        if ((t) + 1 < NT) {                                                 \
            const short* sAn = sA[((t) + 1) & 1];                           \
            const short* sBn = sB[((t) + 1) & 1];                           \
            LDA_HALF(afr, sAn, 0)                                           \
            LDB_PAIR(B23, sBn, 0)                                           \
        }                                                                   \
        BAR();                                                              \
    } while (0)

template<int NPLANES, int SPLIT_OUT, int KT>
__global__ __launch_bounds__(512, 2) void gemm8(
    const short* __restrict__ Ahi, const short* __restrict__ Alo,
    const short* __restrict__ Bhi, const short* __restrict__ Blo,
    float* __restrict__ C, short* __restrict__ Chi, short* __restrict__ Clo,
    int lda, int ldb, int ldc, size_t sAz, size_t sBz, size_t sCz)
{
    constexpr int NT = NPLANES * KT;          // K-tiles of 64 (even for all uses)
    __shared__ short sA[2][16384];            // [buf][256 rows * 64 k]
    __shared__ short sB[2][16384];

    const int tid  = threadIdx.x;
    const int lane = tid & 63, wid = tid >> 6;
    const int wm = (wid >> 2) << 7;           // 0 / 128
    const int wn = (wid & 3) << 6;            // 0 / 64 / 128 / 192
    const int l15 = lane & 15, l4 = lane >> 4, l7 = lane & 7;
    // staging: thread covers physical 16B slot (tid&7) of row (tid>>3);
    // fetch logical slot (tid&7)^(row&7)  (inverse-swizzle on source, m173)
    const int sr   = tid >> 3;
    const int colS = ((tid & 7) ^ (sr & 7)) << 3;   // shorts
    const int wvB  = wid << 9;                       // wave LDS base (shorts)

    // XCD-bijective block swizzle (T1): all grids here have nwg % 8 == 0.
    const unsigned nx = gridDim.x, ny = gridDim.y;
    const unsigned nwg = nx * ny * gridDim.z;
    unsigned flat = blockIdx.x + nx * (blockIdx.y + ny * blockIdx.z);
    if ((nwg & 7u) == 0u) flat = (flat & 7u) * (nwg >> 3) + (flat >> 3);
    const unsigned bx = flat % nx;
    const unsigned rem = flat / nx;
    const unsigned by = rem % ny;
    const unsigned bz = rem / ny;

    const size_t z    = bz;
    const size_t row0 = (size_t)by << 8;
    const size_t col0 = (size_t)bx << 8;
    const short* Abh = Ahi + z * sAz + row0 * (size_t)lda;
    const short* Abl = (NPLANES == 3) ? Alo + z * sAz + row0 * (size_t)lda : nullptr;
    const short* Bbh = Bhi + z * sBz + col0 * (size_t)ldb;
    const short* Bbl = (NPLANES == 3) ? Blo + z * sBz + col0 * (size_t)ldb : nullptr;

    auto aSrc = [&](int t) -> const short* {
        const int p = t / KT;                                  // constexpr KT
        const short* base = (NPLANES == 3 && p == 2) ? Abl : Abh;
        return base + ((t - p * KT) << 6);
    };
    auto bSrc = [&](int t) -> const short* {
        const int p = t / KT;
        const short* base = (NPLANES == 3 && p == 1) ? Bbl : Bbh;
        return base + ((t - p * KT) << 6);
    };
    auto stageA = [&](int t, int h) {                          // half = 128 rows, 2 insts
        const short* g = aSrc(t) + (size_t)((h << 7) + sr) * lda + colS;
        short* l = &sA[t & 1][(h << 13) + wvB];
        gld16(g, l);
        gld16(g + (size_t)(lda << 6), l + 4096);
    };
    auto stageB = [&](int t, int h) {
        const short* g = bSrc(t) + (size_t)((h << 7) + sr) * ldb + colS;
        short* l = &sB[t & 1][(h << 13) + wvB];
        gld16(g, l);
        gld16(g + (size_t)(ldb << 6), l + 4096);
    };

    f32x4 acc[8][4];
    #pragma unroll
    for (int i = 0; i < 8; ++i)
        #pragma unroll
        for (int j = 0; j < 4; ++j)
            acc[i][j] = (f32x4){0.f, 0.f, 0.f, 0.f};

    bf16x8 afr[4][2];          // A half fragments (role: lo -> hi -> lo')
    bf16x8 bC[2][2], bD[2][2]; // B pair groups, roles swap each tile

    // prologue: tile0 fully; tile1 staged in steady-state issue order
    stageB(0, 0); stageB(0, 1); stageA(0, 0); stageA(0, 1);    // 8 insts
    stageB(1, 0);                                              // 2  (like P3)
    stageA(1, 0); stageA(1, 1); stageB(1, 1);                  // 6  (like P4)
    asm volatile("s_waitcnt vmcnt(8)" ::: "memory");           // tile0 landed
    BAR();
    LDA_HALF(afr, sA[0], 0)    // Alo(0)
    LDB_PAIR(bC, sB[0], 0)     // B01(0)

    #pragma unroll 1
    for (int t = 0; t < NT; t += 2) {
        TILE(t, bC, bD);       // even: B01 in bC, B01(t+1) lands in bD
        TILE(t + 1, bD, bC);   // odd:  B01 in bD, B01(t+2) lands in bC
    }

    // C/D layout (16x16x32): col = lane&15, row = (lane>>4)*4 + reg  [m89/m91]
    if (SPLIT_OUT) {
        #pragma unroll
        for (int mf = 0; mf < 8; ++mf)
            #pragma unroll
            for (int nf = 0; nf < 4; ++nf)
                #pragma unroll
                for (int r = 0; r < 4; ++r) {
                    const float x = acc[mf][nf][r];
                    const short h = f2bf(x);
                    const short lo = f2bf(x - bf2f(h));
                    const size_t idx = (row0 + wm + (mf << 4) + (l4 << 2) + r) * (size_t)ldc
                                       + col0 + wn + (nf << 4) + l15;
                    Chi[idx] = h;
                    Clo[idx] = lo;
                }
    } else {
        float* Cb = C + z * sCz;
        #pragma unroll
        for (int mf = 0; mf < 8; ++mf)
            #pragma unroll
            for (int nf = 0; nf < 4; ++nf)
                #pragma unroll
                for (int r = 0; r < 4; ++r)
                    Cb[(row0 + wm + (mf << 4) + (l4 << 2) + r) * (size_t)ldc
                       + col0 + wn + (nf << 4) + l15] = acc[mf][nf][r];
    }
}

// ---------------------------------------------------------------------------
// FALLBACK (ws too small for bf16 alignment copy):
// context = A[M,K] . Bt[N,K]^T; A fp32 (fused bf16 convert), Bt bf16
// ---------------------------------------------------------------------------
__global__ __launch_bounds__(256, 2) void gemm_ctx(
    const float* __restrict__ A, const short* __restrict__ Bt, float* __restrict__ C,
    int lda, int ldb, int ldc, int K, size_t sA, size_t sB, size_t sC)
{
    __shared__ short sA16[128 * 32], sB16[128 * 32];
    const int tid = threadIdx.x;
    const int lane = tid & 63, wave = tid >> 6;
    const int wm = (wave >> 1) << 6, wn = (wave & 1) << 6;
    const int l15 = lane & 15, l4 = lane >> 4;
    const int lr = lane >> 2, lc = (lane & 3) << 3;
    const size_t row0 = (size_t)blockIdx.y << 7, col0 = (size_t)blockIdx.x << 7;
    const float* Ab = A + (size_t)blockIdx.z * sA + row0 * (size_t)lda;
    const short* Bb = Bt + (size_t)blockIdx.z * sB + col0 * (size_t)ldb;

    f32x4 acc[4][4];
    for (int i = 0; i < 4; ++i)
        for (int j = 0; j < 4; ++j)
            acc[i][j] = (f32x4){0.f, 0.f, 0.f, 0.f};

    for (int kt = 0; kt < K; kt += 32) {
        __syncthreads();
        for (int r = 0; r < 4; ++r) {
            const int flat = (r << 8) + tid;
            const int row = flat >> 3, c = (flat & 7) << 2;
            const float4 va = *(const float4*)(Ab + (size_t)row * lda + kt + c);
            short4 h;
            h.x = f2bf(va.x); h.y = f2bf(va.y); h.z = f2bf(va.z); h.w = f2bf(va.w);
            *(short4*)&sA16[(row << 5) + c] = h;
        }
        for (int t = 0; t < 2; ++t) {
            const int rbase = (wave << 5) + (t << 4);
            gld16(Bb + (size_t)(rbase + lr) * ldb + kt + lc, &sB16[rbase << 5]);
        }
        __syncthreads();
        const int ko = l4 << 3;
        bf16x8 ah[4], bh[4];
        for (int i = 0; i < 4; ++i) {
            ah[i] = *(const bf16x8*)&sA16[((wm + (i << 4) + l15) << 5) + ko];
            bh[i] = *(const bf16x8*)&sB16[((wn + (i << 4) + l15) << 5) + ko];
        }
        for (int i = 0; i < 4; ++i)
            for (int j = 0; j < 4; ++j)
                acc[i][j] = __builtin_amdgcn_mfma_f32_16x16x32_bf16(ah[i], bh[j], acc[i][j], 0, 0, 0);
    }

    float* Cb = C + (size_t)blockIdx.z * sC;
    for (int i = 0; i < 4; ++i)
        for (int j = 0; j < 4; ++j)
            for (int r = 0; r < 4; ++r)
                Cb[(row0 + wm + (i << 4) + (l4 << 2) + r) * (size_t)ldc
                   + col0 + wn + (j << 4) + l15] = acc[i][j][r];
}

// elementwise fp32 -> (hi,lo) bf16 planes, 4 elems/thread
__global__ __launch_bounds__(256) void split_f32(
    const float* __restrict__ X, short* __restrict__ hi, short* __restrict__ lo)
{
    const size_t i = ((size_t)blockIdx.x * 256 + threadIdx.x) << 2;
    const float4 v = *(const float4*)(X + i);
    short4 h, l;
    h.x = f2bf(v.x); l.x = f2bf(v.x - bf2f(h.x));
    h.y = f2bf(v.y); l.y = f2bf(v.y - bf2f(h.y));
    h.z = f2bf(v.z); l.z = f2bf(v.z - bf2f(h.z));
    h.w = f2bf(v.w); l.w = f2bf(v.w - bf2f(h.w));
    *(short4*)(hi + i) = h;
    *(short4*)(lo + i) = l;
}

// values[b][v][d] -> Vhi/Vlo (same layout) + Vt[b][d][v] bf16 (hi only)
__global__ __launch_bounds__(256) void split_values(
    const float* __restrict__ V, short* __restrict__ Vhi,
    short* __restrict__ Vlo, short* __restrict__ Vt)
{
    __shared__ float tile[32][33];
    const int b = blockIdx.z;
    const int d0 = blockIdx.x << 5, v0 = blockIdx.y << 5;
    const float* Vb = V + (size_t)b * TV_ * D_;
    const size_t pb = (size_t)b * TV_ * D_;
    short* Vtb = Vt + (size_t)b * D_ * TV_;
    const int tx = threadIdx.x, ty = threadIdx.y;   // 32 x 8
    for (int k = 0; k < 4; ++k) {
        const int v = v0 + ty + (k << 3);
        const float x = Vb[(size_t)v * D_ + d0 + tx];
        tile[ty + (k << 3)][tx] = x;
        const short h = f2bf(x);
        Vhi[pb + (size_t)v * D_ + d0 + tx] = h;
        Vlo[pb + (size_t)v * D_ + d0 + tx] = f2bf(x - bf2f(h));
    }
    __syncthreads();
    for (int k = 0; k < 4; ++k)
        Vtb[(size_t)(d0 + ty + (k << 3)) * TV_ + v0 + tx] = f2bf(tile[tx][ty + (k << 3)]);
}

// in-place softmax over rows of length 2048; optional bf16 copy for ctx GEMM
__global__ __launch_bounds__(256) void softmax_rows(
    float* __restrict__ S, short* __restrict__ A16)
{
    float* p = S + (size_t)blockIdx.x * TV_;
    const int t = threadIdx.x;
    const int lane = t & 63, wave = t >> 6;
    float4 a = *(const float4*)(p + (t << 2));
    float4 b = *(const float4*)(p + 1024 + (t << 2));
    float m = fmaxf(fmaxf(fmaxf(a.x, a.y), fmaxf(a.z, a.w)),
                    fmaxf(fmaxf(b.x, b.y), fmaxf(b.z, b.w)));
    for (int off = 32; off; off >>= 1) m = fmaxf(m, __shfl_xor(m, off, 64));
    __shared__ float redm[4], reds[4];
    if (lane == 0) redm[wave] = m;
    __syncthreads();
    m = fmaxf(fmaxf(redm[0], redm[1]), fmaxf(redm[2], redm[3]));
    a.x = __expf(a.x - m); a.y = __expf(a.y - m);
    a.z = __expf(a.z - m); a.w = __expf(a.w - m);
    b.x = __expf(b.x - m); b.y = __expf(b.y - m);
    b.z = __expf(b.z - m); b.w = __expf(b.w - m);
    float s = a.x + a.y + a.z + a.w + b.x + b.y + b.z + b.w;
    for (int off = 32; off; off >>= 1) s += __shfl_xor(s, off, 64);
    if (lane == 0) reds[wave] = s;
    __syncthreads();
    s = reds[0] + reds[1] + reds[2] + reds[3];
    const float inv = 1.0f / s;
    a.x *= inv; a.y *= inv; a.z *= inv; a.w *= inv;
    b.x *= inv; b.y *= inv; b.z *= inv; b.w *= inv;
    *(float4*)(p + (t << 2)) = a;
    *(float4*)(p + 1024 + (t << 2)) = b;
    if (A16) {
        short* q = A16 + (size_t)blockIdx.x * TV_;
        short4 ha, hb;
        ha.x = f2bf(a.x); ha.y = f2bf(a.y); ha.z = f2bf(a.z); ha.w = f2bf(a.w);
        hb.x = f2bf(b.x); hb.y = f2bf(b.y); hb.z = f2bf(b.z); hb.w = f2bf(b.w);
        *(short4*)(q + (t << 2)) = ha;
        *(short4*)(q + 1024 + (t << 2)) = hb;
    }
}

extern "C" void kernel_launch(void* const* d_in, const int* in_sizes, int n_in,
                              void* d_out, int out_size, void* d_ws, size_t ws_size,
                              hipStream_t stream)
{
    const float* query  = (const float*)d_in[0];   // [16,2048,1024]
    const float* values = (const float*)d_in[1];   // [16,2048,1024]
    const float* Wk     = (const float*)d_in[2];   // [1024,1024]  (bias unused)

    const size_t NQ = (size_t)B_ * TQ_ * D_;       // 33554432
    const size_t NV = (size_t)B_ * TV_ * D_;
    const size_t NW = (size_t)D_ * U_;             // 1048576
    const size_t NA = (size_t)B_ * TQ_ * TV_;      // 67108864

    float* context = (float*)d_out;                          // [16,2048,1024] fp32
    float* align   = (float*)d_out + NQ;                     // [16,2048,2048] fp32

    // context region doubles as P planes (dead before context written)
    short* Phi = (short*)d_out;
    short* Plo = Phi + NQ;
    // align region doubles as Q planes (dead before S written)
    short* Qhi = (short*)align;
    short* Qlo = Qhi + NQ;
    // ws: W planes (4MB) + V planes (128MB) + Vt (64MB) [+ A16 bf16 copy 128MB]
    short* Whi = (short*)d_ws;
    short* Wlo = Whi + NW;
    short* Vhi = Wlo + NW;
    short* Vlo = Vhi + NV;
    short* Vt  = Vlo + NV;
    const size_t WS_NEED = (2 * NW + 3 * NV + NA) * sizeof(short);
    short* A16 = (ws_size >= WS_NEED) ? (Vt + NV) : nullptr;

    // 1. splits
    split_f32<<<NQ / 1024, 256, 0, stream>>>(query, Qhi, Qlo);
    split_f32<<<NW / 1024, 256, 0, stream>>>(Wk, Whi, Wlo);
    split_values<<<dim3(D_ / 32, TV_ / 32, B_), dim3(32, 8), 0, stream>>>(
        values, Vhi, Vlo, Vt);

    // 2. P = Q @ W^T  (M=32768, N=1024, K'=3*1024) -> (Phi,Plo) planes
    gemm8<3, 1, 16><<<dim3(D_ / 256, (B_ * TQ_) / 256, 1), 512, 0, stream>>>(
        Qhi, Qlo, Whi, Wlo, nullptr, Phi, Plo, U_, U_, D_, 0, 0, 0);

    // 3. S = P @ V^T per batch (M=N=2048, K'=3*1024) -> raw scores into align
    gemm8<3, 0, 16><<<dim3(TV_ / 256, TQ_ / 256, B_), 512, 0, stream>>>(
        Phi, Plo, Vhi, Vlo, align, nullptr, nullptr, D_, D_, TV_,
        (size_t)TQ_ * D_, (size_t)TV_ * D_, (size_t)TQ_ * TV_);

    // 4. softmax in place (+ bf16 copy when ws allows)
    softmax_rows<<<B_ * TQ_, 256, 0, stream>>>(align, A16);

    // 5. context = alignment @ V per batch
    if (A16)
        gemm8<1, 0, 32><<<dim3(D_ / 256, TQ_ / 256, B_), 512, 0, stream>>>(
            A16, nullptr, Vt, nullptr, context, nullptr, nullptr, TV_, TV_, D_,
            (size_t)TQ_ * TV_, (size_t)D_ * TV_, (size_t)TQ_ * D_);
    else
        gemm_ctx<<<dim3(D_ / 128, TQ_ / 128, B_), 256, 0, stream>>>(
            align, Vt, context, TV_, TV_, D_, TV_,
            (size_t)TQ_ * TV_, (size_t)D_ * TV_, (size_t)TQ_ * D_);
}